// Round 8
// baseline (74.739 us; speedup 1.0000x reference)
//
#include <hip/hip_runtime.h>
#include <math.h>

#define BB 2
#define NN 384
#define PP 128
#define HH 64
#define EE 32
#define NP 512
#define K1S 136   // w1p LDS stride (bf16): 272B
#define K2S 72    // w2p/tw1p/tw2p stride: 144B

// output layout: upd_q | upd_x | upd_torsions | o  (flat, fp32)
#define X_OFF (BB*NN*4)
#define T_OFF (X_OFF + BB*NN*3)
#define O_OFF (T_OFF + BB*NN*14)

using bf16x8 = __attribute__((ext_vector_type(8))) __bf16;
using f32x4  = __attribute__((ext_vector_type(4))) float;

__device__ __forceinline__ f32x4 MFMA(bf16x8 a, bf16x8 b, f32x4 c) {
  return __builtin_amdgcn_mfma_f32_16x16x32_bf16(a, b, c, 0, 0, 0);
}
// LDS fragment read (element offset into a __bf16 array)
__device__ __forceinline__ bf16x8 LDF(const __bf16* base, int off) {
  return *(const bf16x8*)(base + off);
}
// pack two f32x4 into bf16x8
__device__ __forceinline__ bf16x8 pack8(f32x4 lo, f32x4 hi) {
  bf16x8 r;
  r[0]=(__bf16)lo[0]; r[1]=(__bf16)lo[1]; r[2]=(__bf16)lo[2]; r[3]=(__bf16)lo[3];
  r[4]=(__bf16)hi[0]; r[5]=(__bf16)hi[1]; r[6]=(__bf16)hi[2]; r[7]=(__bf16)hi[3];
  return r;
}
__device__ __forceinline__ bf16x8 pack8v(float4 lo, float4 hi) {
  bf16x8 r;
  r[0]=(__bf16)lo.x; r[1]=(__bf16)lo.y; r[2]=(__bf16)lo.z; r[3]=(__bf16)lo.w;
  r[4]=(__bf16)hi.x; r[5]=(__bf16)hi.y; r[6]=(__bf16)hi.z; r[7]=(__bf16)hi.w;
  return r;
}
// Column permutation: n(t,q) = (t>>1)*32 + (q>>2)*8 + (t&1)*4 + (q&3).
// rowpos(n) = t*16+q, the inverse: which (tile,row) holds output column n.
__device__ __forceinline__ int rowpos(int n) {
  const int t = (n>>5)*2 + ((n>>2)&1);
  const int q = ((n>>3)&3)*4 + (n&3);
  return t*16 + q;
}

// FULLY FUSED: one block = one (b,i) node, 8 waves x 512 threads.
// Edge phase: wave w handles edges w*64..w*64+63 in 2 double-strips of 32
// (weight A-frag ds_reads shared by strips A,B — R5). Node phase fused as a
// tail: o / dq->upd_q / upd_x / torsions computed from s_msum & s_gdx with
// 512-thread 8-part shuffle-reduced matvecs. Removes 2 of 3 dispatches, the
// msum/gdx global round-trip, and the node kernel's serial matvecs (R6
// lesson: an extra dispatch costs more than 4us of edge-kernel savings).
// launch_bounds 2nd arg is BLOCKS/CU (verified R1): (512,2) -> 128-reg cap.
__global__ __launch_bounds__(512, 2) void egnn_fused(
    const float* __restrict__ frames_q, const float* __restrict__ frames_x,
    const float* __restrict__ h, const float* __restrict__ e,
    const int* __restrict__ node_mask,
    const float* __restrict__ pocket_h, const float* __restrict__ pe,
    const float* __restrict__ pocket_q, const float* __restrict__ pocket_x,
    const int* __restrict__ pocket_mask,
    const float* __restrict__ w1, const float* __restrict__ b1,
    const float* __restrict__ w2, const float* __restrict__ b2,
    const float* __restrict__ tw1, const float* __restrict__ tb1,
    const float* __restrict__ tw2, const float* __restrict__ tb2,
    const float* __restrict__ fw1, const float* __restrict__ fb1,
    const float* __restrict__ fw2, const float* __restrict__ fb2,
    const float* __restrict__ qw1, const float* __restrict__ qb1,
    const float* __restrict__ qw2, const float* __restrict__ qb2,
    const float* __restrict__ tow1, const float* __restrict__ tob1,
    const float* __restrict__ tow2, const float* __restrict__ tob2,
    float* __restrict__ out)
{
  __shared__ __align__(16) __bf16 s_w1p[64*K1S];   // permuted W1^T (k-dim 0..127)
  __shared__ __align__(16) __bf16 s_w2p[64*K2S];   // permuted W2^T
  __shared__ __align__(16) __bf16 s_tw1p[64*K2S];  // permuted tw1^T
  __shared__ __align__(16) __bf16 s_tw2p[16*K2S];  // tw2^T (rows 0..2 = dims)
  __shared__ __align__(16) __bf16 s_geo[NP*16 + 8]; // per-edge bf3 frag (+zero slot)
  __shared__ __align__(16) float s_qn[NP*4];       // normalized q_all
  __shared__ float s_maskf[NP];
  __shared__ __align__(16) float s_b2[64], s_tb1[64];
  __shared__ float s_tb2[4];
  __shared__ float s_msum[64], s_gdx[3];
  // fused node-phase buffers
  __shared__ float s_hi[64];
  __shared__ float s_hido[64], s_hidq[64], s_hidt[64];
  __shared__ float s_tmpq[4], s_tmpt[14];
  __shared__ int   s_wcnt[8];

  const int tid = threadIdx.x;
  const int b = blockIdx.x / NN, i = blockIdx.x % NN;

  // ---- stage permuted weights to LDS (bf16); skip k==105 (matvec writes it) ----
  for (int idx = tid; idx < 64*128; idx += 512) {
    const int n = idx & 63, k = idx >> 6;
    float v = 0.f;
    if      (k < 64)  v = w1[(64 + k)*64 + n];         // h_j rows
    else if (k < 96)  v = w1[(128 + (k-64))*64 + n];   // e rows
    else if (k < 105) v = w1[(160 + (k-96))*64 + n];   // geom rows (lx,lq,d2,qdot)
    if (k != 105) s_w1p[rowpos(n)*K1S + k] = (__bf16)v;
  }
  for (int idx = tid; idx < 64*64; idx += 512) {
    const int n = idx & 63, k = idx >> 6;
    s_w2p[rowpos(n)*K2S + k]  = (__bf16)w2[k*64 + n];
    s_tw1p[rowpos(n)*K2S + k] = (__bf16)tw1[k*64 + n];
  }
  for (int idx = tid; idx < 16*64; idx += 512) {
    const int row = idx >> 6, k = idx & 63;
    s_tw2p[row*K2S + k] = (__bf16)((row < 3) ? tw2[k*3 + row] : 0.f);
  }
  if (tid < 64) {
    s_b2[tid] = b2[tid]; s_tb1[tid] = tb1[tid]; s_msum[tid] = 0.f;
    s_hi[tid] = h[(b*NN + i)*HH + tid];
  }
  if (tid < 8)  s_geo[NP*16 + tid] = (__bf16)0.f;      // zero slot for lg>=2
  if (tid < 3)  { s_tb2[tid] = tb2[tid]; s_gdx[tid] = 0.f; }

  // ---- base_i = b1 + h_i @ W1[0:64] -> column k=105 (feat[105] = 1.0) ----
  // parallel over all 512 threads: 8 lanes per output column, shuffle-reduce.
  {
    const int n = tid >> 3, part = tid & 7;
    const float* hi = &h[(b*NN + i)*HH];
    float a = 0.f;
#pragma unroll
    for (int c = 0; c < 8; ++c) a = fmaf(hi[part*8 + c], w1[(part*8 + c)*64 + n], a);
    a += __shfl_xor(a, 1); a += __shfl_xor(a, 2); a += __shfl_xor(a, 4);
    if (part == 0) s_w1p[rowpos(n)*K1S + 105] = (__bf16)(a + b1[n]);
  }

  // ---- per-edge geometry precompute: one thread per j ----
  {
    const int j = tid;   // 512 threads == NP edges
    const int maski = node_mask[b*NN + i];
    const float qi0 = frames_q[(b*NN+i)*4+0], qi1 = frames_q[(b*NN+i)*4+1],
                qi2 = frames_q[(b*NN+i)*4+2], qi3 = frames_q[(b*NN+i)*4+3];
    const float xi0 = frames_x[(b*NN+i)*3+0], xi1 = frames_x[(b*NN+i)*3+1],
                xi2 = frames_x[(b*NN+i)*3+2];
    float qj0,qj1,qj2,qj3, xj0,xj1,xj2; int mj, raw;
    if (j < NN) {
      const float4 q4 = *(const float4*)&frames_q[(b*NN+j)*4];
      qj0=q4.x; qj1=q4.y; qj2=q4.z; qj3=q4.w;
      xj0=frames_x[(b*NN+j)*3+0]; xj1=frames_x[(b*NN+j)*3+1]; xj2=frames_x[(b*NN+j)*3+2];
      raw = (node_mask[b*NN+j] != 0);
      mj  = raw && (j != i);
    } else {
      const int jp = j - NN;
      const float4 q4 = *(const float4*)&pocket_q[(b*PP+jp)*4];
      qj0=q4.x; qj1=q4.y; qj2=q4.z; qj3=q4.w;
      xj0=pocket_x[(b*PP+jp)*3+0]; xj1=pocket_x[(b*PP+jp)*3+1]; xj2=pocket_x[(b*PP+jp)*3+2];
      raw = (pocket_mask[b*PP+jp] != 0);
      mj  = raw;
    }
    // per-wave mask population count (for n_nb in the fused node tail)
    {
      const unsigned long long bal = __ballot(raw);
      if ((tid & 63) == 0) s_wcnt[tid >> 6] = __popcll(bal);
    }
    const float v0 = xi0 - xj0, v1 = xi1 - xj1, v2 = xi2 - xj2;
    const float d2 = v0*v0 + v1*v1 + v2*v2;
    const float qdot = fabsf(qi0*qj0 + qi1*qj1 + qi2*qj2 + qi3*qj3);
    const float cw = qj0, cx = -qj1, cy = -qj2, cz = -qj3;
    const float t0 = 2.f*(cy*v2 - cz*v1);
    const float t1 = 2.f*(cz*v0 - cx*v2);
    const float t2 = 2.f*(cx*v1 - cy*v0);
    const float lx0 = v0 + cw*t0 + (cy*t2 - cz*t1);
    const float lx1 = v1 + cw*t1 + (cz*t0 - cx*t2);
    const float lx2 = v2 + cw*t2 + (cx*t1 - cy*t0);
    const float lq0 = cw*qi0 - cx*qi1 - cy*qi2 - cz*qi3;
    const float lq1 = cw*qi1 + cx*qi0 + cy*qi3 - cz*qi2;
    const float lq2 = cw*qi2 - cx*qi3 + cy*qi0 + cz*qi1;
    const float lq3 = cw*qi3 + cx*qi2 - cy*qi1 + cz*qi0;
    __bf16* g = &s_geo[j*16];
    g[0]=(__bf16)lx0; g[1]=(__bf16)lx1; g[2]=(__bf16)lx2; g[3]=(__bf16)lq0;
    g[4]=(__bf16)lq1; g[5]=(__bf16)lq2; g[6]=(__bf16)lq3; g[7]=(__bf16)d2;
    g[8]=(__bf16)qdot; g[9]=(__bf16)1.f;
    g[10]=(__bf16)0.f; g[11]=(__bf16)0.f; g[12]=(__bf16)0.f;
    g[13]=(__bf16)0.f; g[14]=(__bf16)0.f; g[15]=(__bf16)0.f;
    s_maskf[j] = (maski && mj) ? 1.f : 0.f;
    const float inv = 1.f / fmaxf(sqrtf(qj0*qj0 + qj1*qj1 + qj2*qj2 + qj3*qj3), 1e-12f);
    float4* qn = (float4*)&s_qn[j*4];
    *qn = make_float4(qj0*inv, qj1*inv, qj2*inv, qj3*inv);
  }
  __syncthreads();

  const int wv = tid >> 6, lane = tid & 63;
  const int l15 = lane & 15, lg = lane >> 4;

  // ---- per-wave register prologue (small stuff only) ----
  bf16x8 tw2f[2];
  tw2f[0] = *(const bf16x8*)&s_tw2p[l15*K2S +  0 + lg*8];
  tw2f[1] = *(const bf16x8*)&s_tw2p[l15*K2S + 32 + lg*8];
  const float tb2r0 = s_tb2[0], tb2r1 = s_tb2[1], tb2r2 = s_tb2[2];

  float msacc[16];
#pragma unroll
  for (int v = 0; v < 16; ++v) msacc[v] = 0.f;
  float gx0 = 0.f, gx1 = 0.f, gx2 = 0.f;

  const int o1base = l15*K1S + lg*8;   // W1 frag base (element offset)
  const int o2base = l15*K2S + lg*8;   // W2 / tw1 frag base
  const int obbase = lg*8;             // bias f32x4 base (float offset)

  // load strip data (16 edges starting at JB0)
#define LOADSTRIP(JB0, H0_,H1_,H2_,H3_,E0_,E1_) do {                        \
    const int jb_ = (JB0);                                                  \
    const int j_ = jb_ + l15;                                               \
    const float *hj_, *ej_;                                                 \
    if (jb_ < NN) {                                                         \
      hj_ = &h[(b*NN + j_)*HH];                                             \
      ej_ = &e[((b*NN + i)*NN + j_)*EE];                                    \
    } else {                                                                \
      const int jp_ = j_ - NN;                                              \
      hj_ = &pocket_h[(b*PP + jp_)*HH];                                     \
      ej_ = &pe[((b*NN + i)*PP + jp_)*EE];                                  \
    }                                                                       \
    H0_ = *(const float4*)&hj_[lg*8];                                       \
    H1_ = *(const float4*)&hj_[lg*8 + 4];                                   \
    H2_ = *(const float4*)&hj_[32 + lg*8];                                  \
    H3_ = *(const float4*)&hj_[32 + lg*8 + 4];                              \
    E0_ = *(const float4*)&ej_[lg*8];                                       \
    E1_ = *(const float4*)&ej_[lg*8 + 4];                                   \
  } while (0)

#pragma unroll
  for (int ss = 0; ss < 2; ++ss) {
    // per-iteration launder: keeps weight-frag/bias LDS reads inside the
    // loop (LICM would hoist them into registers and blow the 128 budget)
    int o1 = o1base; asm volatile("" : "+v"(o1));
    int o2 = o2base; asm volatile("" : "+v"(o2));
    int ob = obbase; asm volatile("" : "+v"(ob));

    const int jbA = wv*64 + ss*32;
    const int jbB = jbA + 16;
    const int jA = jbA + l15, jB = jbB + l15;

    float4 hA0,hA1,hA2,hA3,eA0,eA1, hB0,hB1,hB2,hB3,eB0,eB1;
    LOADSTRIP(jbA, hA0,hA1,hA2,hA3,eA0,eA1);
    LOADSTRIP(jbB, hB0,hB1,hB2,hB3,eB0,eB1);
    const float maskA = s_maskf[jA];
    const float maskB = s_maskf[jB];

    // B-fragments for both strips
    const bf16x8 bfA0 = pack8v(hA0, hA1);
    const bf16x8 bfA1 = pack8v(hA2, hA3);
    const bf16x8 bfA2 = pack8v(eA0, eA1);
    const bf16x8 bfA3 = *(const bf16x8*)&s_geo[(lg < 2) ? (jA*16 + lg*8) : NP*16];
    const bf16x8 bfB0 = pack8v(hB0, hB1);
    const bf16x8 bfB1 = pack8v(hB2, hB3);
    const bf16x8 bfB2 = pack8v(eB0, eB1);
    const bf16x8 bfB3 = *(const bf16x8*)&s_geo[(lg < 2) ? (jB*16 + lg*8) : NP*16];

    const f32x4 zero4 = {0.f, 0.f, 0.f, 0.f};

    // ---- L1: each W1 frag read feeds both strips ----
    bf16x8 hbA0, hbA1, hbB0, hbB1;
    {
      f32x4 aA0, aA1, aB0, aB1;
      {
        const bf16x8 F0 = LDF(s_w1p, o1 + 0*16*K1S +  0);
        const bf16x8 F1 = LDF(s_w1p, o1 + 0*16*K1S + 32);
        const bf16x8 F2 = LDF(s_w1p, o1 + 0*16*K1S + 64);
        const bf16x8 F3 = LDF(s_w1p, o1 + 0*16*K1S + 96);
        aA0 = MFMA(F0,bfA0,zero4); aA0 = MFMA(F1,bfA1,aA0); aA0 = MFMA(F2,bfA2,aA0); aA0 = MFMA(F3,bfA3,aA0);
        aB0 = MFMA(F0,bfB0,zero4); aB0 = MFMA(F1,bfB1,aB0); aB0 = MFMA(F2,bfB2,aB0); aB0 = MFMA(F3,bfB3,aB0);
      }
      {
        const bf16x8 F0 = LDF(s_w1p, o1 + 1*16*K1S +  0);
        const bf16x8 F1 = LDF(s_w1p, o1 + 1*16*K1S + 32);
        const bf16x8 F2 = LDF(s_w1p, o1 + 1*16*K1S + 64);
        const bf16x8 F3 = LDF(s_w1p, o1 + 1*16*K1S + 96);
        aA1 = MFMA(F0,bfA0,zero4); aA1 = MFMA(F1,bfA1,aA1); aA1 = MFMA(F2,bfA2,aA1); aA1 = MFMA(F3,bfA3,aA1);
        aB1 = MFMA(F0,bfB0,zero4); aB1 = MFMA(F1,bfB1,aB1); aB1 = MFMA(F2,bfB2,aB1); aB1 = MFMA(F3,bfB3,aB1);
      }
#pragma unroll
      for (int r = 0; r < 4; ++r) {
        aA0[r] = fmaxf(aA0[r], 0.f); aA1[r] = fmaxf(aA1[r], 0.f);
        aB0[r] = fmaxf(aB0[r], 0.f); aB1[r] = fmaxf(aB1[r], 0.f);
      }
      hbA0 = pack8(aA0, aA1); hbB0 = pack8(aB0, aB1);
      {
        const bf16x8 F0 = LDF(s_w1p, o1 + 2*16*K1S +  0);
        const bf16x8 F1 = LDF(s_w1p, o1 + 2*16*K1S + 32);
        const bf16x8 F2 = LDF(s_w1p, o1 + 2*16*K1S + 64);
        const bf16x8 F3 = LDF(s_w1p, o1 + 2*16*K1S + 96);
        aA0 = MFMA(F0,bfA0,zero4); aA0 = MFMA(F1,bfA1,aA0); aA0 = MFMA(F2,bfA2,aA0); aA0 = MFMA(F3,bfA3,aA0);
        aB0 = MFMA(F0,bfB0,zero4); aB0 = MFMA(F1,bfB1,aB0); aB0 = MFMA(F2,bfB2,aB0); aB0 = MFMA(F3,bfB3,aB0);
      }
      {
        const bf16x8 F0 = LDF(s_w1p, o1 + 3*16*K1S +  0);
        const bf16x8 F1 = LDF(s_w1p, o1 + 3*16*K1S + 32);
        const bf16x8 F2 = LDF(s_w1p, o1 + 3*16*K1S + 64);
        const bf16x8 F3 = LDF(s_w1p, o1 + 3*16*K1S + 96);
        aA1 = MFMA(F0,bfA0,zero4); aA1 = MFMA(F1,bfA1,aA1); aA1 = MFMA(F2,bfA2,aA1); aA1 = MFMA(F3,bfA3,aA1);
        aB1 = MFMA(F0,bfB0,zero4); aB1 = MFMA(F1,bfB1,aB1); aB1 = MFMA(F2,bfB2,aB1); aB1 = MFMA(F3,bfB3,aB1);
      }
#pragma unroll
      for (int r = 0; r < 4; ++r) {
        aA0[r] = fmaxf(aA0[r], 0.f); aA1[r] = fmaxf(aA1[r], 0.f);
        aB0[r] = fmaxf(aB0[r], 0.f); aB1[r] = fmaxf(aB1[r], 0.f);
      }
      hbA1 = pack8(aA0, aA1); hbB1 = pack8(aB0, aB1);
    }

    // ---- L2: m^T tiles, shared W2 frags, biases as laundered f32x4 LDS reads ----
    bf16x8 mbA0, mbA1, mbB0, mbB1;
    {
      f32x4 cA0, cA1, cB0, cB1;
      {
        const bf16x8 F0 = LDF(s_w2p, o2 + 0*16*K2S +  0);
        const bf16x8 F1 = LDF(s_w2p, o2 + 0*16*K2S + 32);
        cA0 = MFMA(F0,hbA0,zero4); cA0 = MFMA(F1,hbA1,cA0);
        cB0 = MFMA(F0,hbB0,zero4); cB0 = MFMA(F1,hbB1,cB0);
      }
      {
        const bf16x8 F0 = LDF(s_w2p, o2 + 1*16*K2S +  0);
        const bf16x8 F1 = LDF(s_w2p, o2 + 1*16*K2S + 32);
        cA1 = MFMA(F0,hbA0,zero4); cA1 = MFMA(F1,hbA1,cA1);
        cB1 = MFMA(F0,hbB0,zero4); cB1 = MFMA(F1,hbB1,cB1);
      }
      const f32x4 bb0 = *(const f32x4*)&s_b2[ob + 0];
      const f32x4 bb1 = *(const f32x4*)&s_b2[ob + 4];
#pragma unroll
      for (int r = 0; r < 4; ++r) {
        cA0[r] = (cA0[r] + bb0[r]) * maskA;  cB0[r] = (cB0[r] + bb0[r]) * maskB;
        cA1[r] = (cA1[r] + bb1[r]) * maskA;  cB1[r] = (cB1[r] + bb1[r]) * maskB;
        msacc[0*4+r] += cA0[r] + cB0[r];
        msacc[1*4+r] += cA1[r] + cB1[r];
      }
      mbA0 = pack8(cA0, cA1); mbB0 = pack8(cB0, cB1);
      {
        const bf16x8 F0 = LDF(s_w2p, o2 + 2*16*K2S +  0);
        const bf16x8 F1 = LDF(s_w2p, o2 + 2*16*K2S + 32);
        cA0 = MFMA(F0,hbA0,zero4); cA0 = MFMA(F1,hbA1,cA0);
        cB0 = MFMA(F0,hbB0,zero4); cB0 = MFMA(F1,hbB1,cB0);
      }
      {
        const bf16x8 F0 = LDF(s_w2p, o2 + 3*16*K2S +  0);
        const bf16x8 F1 = LDF(s_w2p, o2 + 3*16*K2S + 32);
        cA1 = MFMA(F0,hbA0,zero4); cA1 = MFMA(F1,hbA1,cA1);
        cB1 = MFMA(F0,hbB0,zero4); cB1 = MFMA(F1,hbB1,cB1);
      }
      const f32x4 bb2 = *(const f32x4*)&s_b2[ob + 32];
      const f32x4 bb3 = *(const f32x4*)&s_b2[ob + 36];
#pragma unroll
      for (int r = 0; r < 4; ++r) {
        cA0[r] = (cA0[r] + bb2[r]) * maskA;  cB0[r] = (cB0[r] + bb2[r]) * maskB;
        cA1[r] = (cA1[r] + bb3[r]) * maskA;  cB1[r] = (cB1[r] + bb3[r]) * maskB;
        msacc[2*4+r] += cA0[r] + cB0[r];
        msacc[3*4+r] += cA1[r] + cB1[r];
      }
      mbA1 = pack8(cA0, cA1); mbB1 = pack8(cB0, cB1);
    }

    // ---- tr1: th^T tiles, shared tw1 frags ----
    bf16x8 thbA0, thbA1, thbB0, thbB1;
    {
      f32x4 dA0, dA1, dB0, dB1;
      {
        const bf16x8 F0 = LDF(s_tw1p, o2 + 0*16*K2S +  0);
        const bf16x8 F1 = LDF(s_tw1p, o2 + 0*16*K2S + 32);
        dA0 = MFMA(F0,mbA0,zero4); dA0 = MFMA(F1,mbA1,dA0);
        dB0 = MFMA(F0,mbB0,zero4); dB0 = MFMA(F1,mbB1,dB0);
      }
      {
        const bf16x8 F0 = LDF(s_tw1p, o2 + 1*16*K2S +  0);
        const bf16x8 F1 = LDF(s_tw1p, o2 + 1*16*K2S + 32);
        dA1 = MFMA(F0,mbA0,zero4); dA1 = MFMA(F1,mbA1,dA1);
        dB1 = MFMA(F0,mbB0,zero4); dB1 = MFMA(F1,mbB1,dB1);
      }
      {
        const f32x4 tb0 = *(const f32x4*)&s_tb1[ob + 0];
        const f32x4 tb1v = *(const f32x4*)&s_tb1[ob + 4];
#pragma unroll
        for (int r = 0; r < 4; ++r) {
          dA0[r] = fmaxf(dA0[r] + tb0[r], 0.f);  dB0[r] = fmaxf(dB0[r] + tb0[r], 0.f);
          dA1[r] = fmaxf(dA1[r] + tb1v[r], 0.f); dB1[r] = fmaxf(dB1[r] + tb1v[r], 0.f);
        }
      }
      thbA0 = pack8(dA0, dA1); thbB0 = pack8(dB0, dB1);
      {
        const bf16x8 F0 = LDF(s_tw1p, o2 + 2*16*K2S +  0);
        const bf16x8 F1 = LDF(s_tw1p, o2 + 2*16*K2S + 32);
        dA0 = MFMA(F0,mbA0,zero4); dA0 = MFMA(F1,mbA1,dA0);
        dB0 = MFMA(F0,mbB0,zero4); dB0 = MFMA(F1,mbB1,dB0);
      }
      {
        const bf16x8 F0 = LDF(s_tw1p, o2 + 3*16*K2S +  0);
        const bf16x8 F1 = LDF(s_tw1p, o2 + 3*16*K2S + 32);
        dA1 = MFMA(F0,mbA0,zero4); dA1 = MFMA(F1,mbA1,dA1);
        dB1 = MFMA(F0,mbB0,zero4); dB1 = MFMA(F1,mbB1,dB1);
      }
      {
        const f32x4 tb2v = *(const f32x4*)&s_tb1[ob + 32];
        const f32x4 tb3v = *(const f32x4*)&s_tb1[ob + 36];
#pragma unroll
        for (int r = 0; r < 4; ++r) {
          dA0[r] = fmaxf(dA0[r] + tb2v[r], 0.f);  dB0[r] = fmaxf(dB0[r] + tb2v[r], 0.f);
          dA1[r] = fmaxf(dA1[r] + tb3v[r], 0.f);  dB1[r] = fmaxf(dB1[r] + tb3v[r], 0.f);
        }
      }
      thbA1 = pack8(dA0, dA1); thbB1 = pack8(dB0, dB1);
    }

    // ---- dx: 2 MFMAs per strip with tw2^T (rows 0..2 = dims) ----
    f32x4 daccA = MFMA(tw2f[0], thbA0, zero4);
    daccA = MFMA(tw2f[1], thbA1, daccA);
    f32x4 daccB = MFMA(tw2f[0], thbB0, zero4);
    daccB = MFMA(tw2f[1], thbB1, daccB);

    if (lg == 0) {
      {
        const float dx0 = (daccA[0] + tb2r0) * maskA;
        const float dx1 = (daccA[1] + tb2r1) * maskA;
        const float dx2 = (daccA[2] + tb2r2) * maskA;
        const float4 qn = *(const float4*)&s_qn[jA*4];
        const float w = qn.x, ux = qn.y, uy = qn.z, uz = qn.w;
        const float r0 = 2.f*(uy*dx2 - uz*dx1);
        const float r1 = 2.f*(uz*dx0 - ux*dx2);
        const float r2 = 2.f*(ux*dx1 - uy*dx0);
        gx0 += dx0 + w*r0 + (uy*r2 - uz*r1);
        gx1 += dx1 + w*r1 + (uz*r0 - ux*r2);
        gx2 += dx2 + w*r2 + (ux*r1 - uy*r0);
      }
      {
        const float dx0 = (daccB[0] + tb2r0) * maskB;
        const float dx1 = (daccB[1] + tb2r1) * maskB;
        const float dx2 = (daccB[2] + tb2r2) * maskB;
        const float4 qn = *(const float4*)&s_qn[jB*4];
        const float w = qn.x, ux = qn.y, uy = qn.z, uz = qn.w;
        const float r0 = 2.f*(uy*dx2 - uz*dx1);
        const float r1 = 2.f*(uz*dx0 - ux*dx2);
        const float r2 = 2.f*(ux*dx1 - uy*dx0);
        gx0 += dx0 + w*r0 + (uy*r2 - uz*r1);
        gx1 += dx1 + w*r1 + (uz*r0 - ux*r2);
        gx2 += dx2 + w*r2 + (ux*r1 - uy*r0);
      }
    }
  }
#undef LOADSTRIP

  // ---- edge epilogue: msum (reduce over the 16 l15 lanes), gdx ----
#pragma unroll
  for (int v = 0; v < 16; ++v) {
    float x = msacc[v];
    x += __shfl_xor(x, 1); x += __shfl_xor(x, 2);
    x += __shfl_xor(x, 4); x += __shfl_xor(x, 8);
    if (l15 == 0) {
      const int n2 = (v>>3)*32 + lg*8 + ((v>>2)&1)*4 + (v&3);
      atomicAdd(&s_msum[n2], x);
    }
  }
  {
    float v0 = (lg == 0) ? gx0 : 0.f;
    float v1 = (lg == 0) ? gx1 : 0.f;
    float v2 = (lg == 0) ? gx2 : 0.f;
#pragma unroll
    for (int sft = 1; sft < 64; sft <<= 1) {
      v0 += __shfl_xor(v0, sft); v1 += __shfl_xor(v1, sft); v2 += __shfl_xor(v2, sft);
    }
    if (lane == 0) { atomicAdd(&s_gdx[0], v0); atomicAdd(&s_gdx[1], v1); atomicAdd(&s_gdx[2], v2); }
  }
  __syncthreads();

  // ==== fused node tail: o / dq->upd_q / upd_x / torsions ====
  // step 1: three hidden layers, 512-thread 8-part shuffle-reduced matvecs
  {
    const int n = tid >> 3, part = tid & 7;
    float ao = 0.f, aq = 0.f, at = 0.f;
#pragma unroll
    for (int c = 0; c < 16; ++c) {
      const int kk = part*16 + c;
      const float x = (kk < 64) ? s_hi[kk] : s_msum[kk - 64];
      ao = fmaf(x, fw1[kk*64 + n], ao);
    }
#pragma unroll
    for (int c = 0; c < 8; ++c) {
      const int kk = part*8 + c;
      aq = fmaf(s_msum[kk], qw1[kk*64 + n], aq);
      at = fmaf(s_msum[kk], tow1[kk*64 + n], at);
    }
    ao += __shfl_xor(ao,1); ao += __shfl_xor(ao,2); ao += __shfl_xor(ao,4);
    aq += __shfl_xor(aq,1); aq += __shfl_xor(aq,2); aq += __shfl_xor(aq,4);
    at += __shfl_xor(at,1); at += __shfl_xor(at,2); at += __shfl_xor(at,4);
    if (part == 0) {
      s_hido[n] = fmaxf(ao + fb1[n], 0.f);
      s_hidq[n] = fmaxf(aq + qb1[n], 0.f);
      s_hidt[n] = fmaxf(at + tob1[n], 0.f);
    }
  }
  __syncthreads();
  // step 2: output layers
  {
    const int n = tid >> 3, part = tid & 7;
    float ov = 0.f;
#pragma unroll
    for (int c = 0; c < 8; ++c) {
      const int kk = part*8 + c;
      ov = fmaf(s_hido[kk], fw2[kk*64 + n], ov);
    }
    ov += __shfl_xor(ov,1); ov += __shfl_xor(ov,2); ov += __shfl_xor(ov,4);
    if (part == 0) out[O_OFF + (b*NN+i)*64 + n] = ov + fb2[n];
  }
  if (tid < 4) {
    float d = qb2[tid];
#pragma unroll 8
    for (int k = 0; k < 64; ++k) d = fmaf(s_hidq[k], qw2[k*4 + tid], d);
    s_tmpq[tid] = d;
  }
  if (tid >= 64 && tid < 78) {
    const int t = tid - 64;
    float v = tob2[t];
#pragma unroll 8
    for (int k = 0; k < 64; ++k) v = fmaf(s_hidt[k], tow2[k*14 + t], v);
    s_tmpt[t] = v;
  }
  __syncthreads();
  // step 3: finalize
  if (tid == 0) {
    const int mi = node_mask[b*NN+i];
    float d0,d1,d2,d3;
    if (mi) { d0=s_tmpq[0]; d1=s_tmpq[1]; d2=s_tmpq[2]; d3=s_tmpq[3]; }
    else    { d0=1.f; d1=0.f; d2=0.f; d3=0.f; }
    float nrm = fmaxf(sqrtf(d0*d0+d1*d1+d2*d2+d3*d3), 1e-12f);
    d0/=nrm; d1/=nrm; d2/=nrm; d3/=nrm;
    const float q0=frames_q[(b*NN+i)*4+0], q1=frames_q[(b*NN+i)*4+1],
                q2=frames_q[(b*NN+i)*4+2], q3=frames_q[(b*NN+i)*4+3];
    float u0 = q0*d0 - q1*d1 - q2*d2 - q3*d3;
    float u1 = q0*d1 + q1*d0 + q2*d3 - q3*d2;
    float u2 = q0*d2 - q1*d3 + q2*d0 + q3*d1;
    float u3 = q0*d3 + q1*d2 - q2*d1 + q3*d0;
    if (!mi) { u0=1.f; u1=0.f; u2=0.f; u3=0.f; }
    float nrm2 = fmaxf(sqrtf(u0*u0+u1*u1+u2*u2+u3*u3), 1e-12f);
    out[(b*NN+i)*4+0]=u0/nrm2; out[(b*NN+i)*4+1]=u1/nrm2;
    out[(b*NN+i)*4+2]=u2/nrm2; out[(b*NN+i)*4+3]=u3/nrm2;
  }
  if (tid >= 4 && tid < 7) {
    const int t = tid - 4;
    const int cnt = s_wcnt[0]+s_wcnt[1]+s_wcnt[2]+s_wcnt[3]
                  + s_wcnt[4]+s_wcnt[5]+s_wcnt[6]+s_wcnt[7];
    const float n_nb = (float)(cnt - 1);
    out[X_OFF + (b*NN+i)*3 + t] = frames_x[(b*NN+i)*3 + t] + s_gdx[t] / n_nb;
  }
  if (tid >= 16 && tid < 30) {
    const int t = tid - 16;
    const int p = t & ~1;
    const float a0 = s_tmpt[p], a1 = s_tmpt[p+1];
    const float nrm = fmaxf(sqrtf(a0*a0 + a1*a1), 1e-12f);
    out[T_OFF + (b*NN+i)*14 + t] = s_tmpt[t] / nrm;
  }
}

extern "C" void kernel_launch(void* const* d_in, const int* in_sizes, int n_in,
                              void* d_out, int out_size, void* d_ws, size_t ws_size,
                              hipStream_t stream) {
  const float* frames_q    = (const float*)d_in[0];
  const float* frames_x    = (const float*)d_in[1];
  const float* h           = (const float*)d_in[3];
  const float* e           = (const float*)d_in[4];
  const int*   node_mask   = (const int*)d_in[5];
  const float* pocket_h    = (const float*)d_in[6];
  const float* pocket_e    = (const float*)d_in[7];
  const float* pocket_q    = (const float*)d_in[8];
  const float* pocket_x    = (const float*)d_in[9];
  const int*   pocket_mask = (const int*)d_in[10];
  const float* msg_w1 = (const float*)d_in[11];
  const float* msg_b1 = (const float*)d_in[12];
  const float* msg_w2 = (const float*)d_in[13];
  const float* msg_b2 = (const float*)d_in[14];
  const float* feat_w1 = (const float*)d_in[15];
  const float* feat_b1 = (const float*)d_in[16];
  const float* feat_w2 = (const float*)d_in[17];
  const float* feat_b2 = (const float*)d_in[18];
  const float* tr_w1 = (const float*)d_in[19];
  const float* tr_b1 = (const float*)d_in[20];
  const float* tr_w2 = (const float*)d_in[21];
  const float* tr_b2 = (const float*)d_in[22];
  const float* qu_w1 = (const float*)d_in[23];
  const float* qu_b1 = (const float*)d_in[24];
  const float* qu_w2 = (const float*)d_in[25];
  const float* qu_b2 = (const float*)d_in[26];
  const float* to_w1 = (const float*)d_in[27];
  const float* to_b1 = (const float*)d_in[28];
  const float* to_w2 = (const float*)d_in[29];
  const float* to_b2 = (const float*)d_in[30];

  float* out = (float*)d_out;

  egnn_fused<<<dim3(BB*NN), dim3(512), 0, stream>>>(
      frames_q, frames_x, h, e, node_mask,
      pocket_h, pocket_e, pocket_q, pocket_x, pocket_mask,
      msg_w1, msg_b1, msg_w2, msg_b2,
      tr_w1, tr_b1, tr_w2, tr_b2,
      feat_w1, feat_b1, feat_w2, feat_b2,
      qu_w1, qu_b1, qu_w2, qu_b2,
      to_w1, to_b1, to_w2, to_b2,
      out);
}

// Round 9
// 59.482 us; speedup vs baseline: 1.2565x; 1.2565x over previous
//
#include <hip/hip_runtime.h>
#include <math.h>

#define BB 2
#define NN 384
#define PP 128
#define HH 64
#define EE 32
#define NP 512
#define K1S 136   // w1p LDS stride (bf16): 272B
#define K2S 72    // w2p/tw1p/tw2p stride: 144B

// output layout: upd_q | upd_x | upd_torsions | o  (flat, fp32)
#define X_OFF (BB*NN*4)
#define T_OFF (X_OFF + BB*NN*3)
#define O_OFF (T_OFF + BB*NN*14)

using bf16x8 = __attribute__((ext_vector_type(8))) __bf16;
using f32x4  = __attribute__((ext_vector_type(4))) float;

__device__ __forceinline__ f32x4 MFMA(bf16x8 a, bf16x8 b, f32x4 c) {
  return __builtin_amdgcn_mfma_f32_16x16x32_bf16(a, b, c, 0, 0, 0);
}
// LDS fragment read (element offset into a __bf16 array)
__device__ __forceinline__ bf16x8 LDF(const __bf16* base, int off) {
  return *(const bf16x8*)(base + off);
}
// pack two f32x4 into bf16x8
__device__ __forceinline__ bf16x8 pack8(f32x4 lo, f32x4 hi) {
  bf16x8 r;
  r[0]=(__bf16)lo[0]; r[1]=(__bf16)lo[1]; r[2]=(__bf16)lo[2]; r[3]=(__bf16)lo[3];
  r[4]=(__bf16)hi[0]; r[5]=(__bf16)hi[1]; r[6]=(__bf16)hi[2]; r[7]=(__bf16)hi[3];
  return r;
}
__device__ __forceinline__ bf16x8 pack8v(float4 lo, float4 hi) {
  bf16x8 r;
  r[0]=(__bf16)lo.x; r[1]=(__bf16)lo.y; r[2]=(__bf16)lo.z; r[3]=(__bf16)lo.w;
  r[4]=(__bf16)hi.x; r[5]=(__bf16)hi.y; r[6]=(__bf16)hi.z; r[7]=(__bf16)hi.w;
  return r;
}
// Column permutation: n(t,q) = (t>>1)*32 + (q>>2)*8 + (t&1)*4 + (q&3).
// rowpos(n) = t*16+q, the inverse: which (tile,row) holds output column n.
__device__ __forceinline__ int rowpos(int n) {
  const int t = (n>>5)*2 + ((n>>2)&1);
  const int q = ((n>>3)&3)*4 + (n&3);
  return t*16 + q;
}

// PERSISTENT: grid = 256 blocks x 1024 threads (16 waves, 1 block/CU).
// Each block processes 3 nodes (ni = bid, bid+256, bid+512). Per node, wave
// wv handles one 32-edge double-strip (strips A,B of 16; weight A-frag
// ds_reads shared by both strips — R5). Weights staged to LDS ONCE per
// block (3x amortization). Rationale (R8 post-mortem): 768-block grid at 2
// blocks/CU = 1.5 residency rounds -> time-weighted occupancy ~21% vs 50%
// static; persistent grid gives every CU 16 waves for the whole kernel.
// launch_bounds 2nd arg is BLOCKS/CU (verified R1): (1024,1) -> 4 waves/EU
// -> 128-reg cap.
__global__ __launch_bounds__(1024, 1) void egnn_edge_persist(
    const float* __restrict__ frames_q, const float* __restrict__ frames_x,
    const float* __restrict__ h, const float* __restrict__ e,
    const int* __restrict__ node_mask,
    const float* __restrict__ pocket_h, const float* __restrict__ pe,
    const float* __restrict__ pocket_q, const float* __restrict__ pocket_x,
    const int* __restrict__ pocket_mask,
    const float* __restrict__ w1, const float* __restrict__ b1,
    const float* __restrict__ w2, const float* __restrict__ b2,
    const float* __restrict__ tw1, const float* __restrict__ tb1,
    const float* __restrict__ tw2, const float* __restrict__ tb2,
    float* __restrict__ msum_ws, float* __restrict__ gdx_ws)
{
  __shared__ __align__(16) __bf16 s_w1p[64*K1S];   // permuted W1^T (k-dim 0..127)
  __shared__ __align__(16) __bf16 s_w2p[64*K2S];   // permuted W2^T
  __shared__ __align__(16) __bf16 s_tw1p[64*K2S];  // permuted tw1^T
  __shared__ __align__(16) __bf16 s_tw2p[16*K2S];  // tw2^T (rows 0..2 = dims)
  __shared__ __align__(16) __bf16 s_geo[NP*16 + 8]; // per-edge bf3 frag (+zero slot)
  __shared__ __align__(16) float s_qn[NP*4];       // normalized q_all
  __shared__ float s_maskf[NP];
  __shared__ __align__(16) float s_b2[64], s_tb1[64];
  __shared__ float s_tb2[4];
  __shared__ float s_msum[64], s_gdx[3];

  const int tid = threadIdx.x;

  // ---- stage permuted weights to LDS ONCE (bf16); skip k==105 ----
  for (int idx = tid; idx < 64*128; idx += 1024) {
    const int n = idx & 63, k = idx >> 6;
    float v = 0.f;
    if      (k < 64)  v = w1[(64 + k)*64 + n];         // h_j rows
    else if (k < 96)  v = w1[(128 + (k-64))*64 + n];   // e rows
    else if (k < 105) v = w1[(160 + (k-96))*64 + n];   // geom rows (lx,lq,d2,qdot)
    if (k != 105) s_w1p[rowpos(n)*K1S + k] = (__bf16)v;
  }
  for (int idx = tid; idx < 64*64; idx += 1024) {
    const int n = idx & 63, k = idx >> 6;
    s_w2p[rowpos(n)*K2S + k]  = (__bf16)w2[k*64 + n];
    s_tw1p[rowpos(n)*K2S + k] = (__bf16)tw1[k*64 + n];
  }
  for (int idx = tid; idx < 16*64; idx += 1024) {
    const int row = idx >> 6, k = idx & 63;
    s_tw2p[row*K2S + k] = (__bf16)((row < 3) ? tw2[k*3 + row] : 0.f);
  }
  if (tid < 64) { s_b2[tid] = b2[tid]; s_tb1[tid] = tb1[tid]; }
  if (tid < 8)  s_geo[NP*16 + tid] = (__bf16)0.f;      // zero slot for lg>=2
  if (tid < 3)  s_tb2[tid] = tb2[tid];
  __syncthreads();

  const int wv = tid >> 6, lane = tid & 63;
  const int l15 = lane & 15, lg = lane >> 4;

  bf16x8 tw2f[2];
  tw2f[0] = *(const bf16x8*)&s_tw2p[l15*K2S +  0 + lg*8];
  tw2f[1] = *(const bf16x8*)&s_tw2p[l15*K2S + 32 + lg*8];
  const float tb2r0 = s_tb2[0], tb2r1 = s_tb2[1], tb2r2 = s_tb2[2];

  const int o1base = l15*K1S + lg*8;   // W1 frag base (element offset)
  const int o2base = l15*K2S + lg*8;   // W2 / tw1 frag base
  const int obbase = lg*8;             // bias f32x4 base (float offset)

  // load strip data (16 edges starting at JB0)
#define LOADSTRIP(JB0, H0_,H1_,H2_,H3_,E0_,E1_) do {                        \
    const int jb_ = (JB0);                                                  \
    const int j_ = jb_ + l15;                                               \
    const float *hj_, *ej_;                                                 \
    if (jb_ < NN) {                                                         \
      hj_ = &h[(b*NN + j_)*HH];                                             \
      ej_ = &e[((b*NN + i)*NN + j_)*EE];                                    \
    } else {                                                                \
      const int jp_ = j_ - NN;                                              \
      hj_ = &pocket_h[(b*PP + jp_)*HH];                                     \
      ej_ = &pe[((b*NN + i)*PP + jp_)*EE];                                  \
    }                                                                       \
    H0_ = *(const float4*)&hj_[lg*8];                                       \
    H1_ = *(const float4*)&hj_[lg*8 + 4];                                   \
    H2_ = *(const float4*)&hj_[32 + lg*8];                                  \
    H3_ = *(const float4*)&hj_[32 + lg*8 + 4];                              \
    E0_ = *(const float4*)&ej_[lg*8];                                       \
    E1_ = *(const float4*)&ej_[lg*8 + 4];                                   \
  } while (0)

#pragma unroll 1
  for (int rep = 0; rep < 3; ++rep) {
    const int ni = (int)blockIdx.x + rep*256;
    const int b = ni / NN, i = ni % NN;

    // protect s_geo/s_gdx/s_msum from previous node's readers/writers
    __syncthreads();
    if (tid < 64) s_msum[tid] = 0.f;
    if (tid < 3)  s_gdx[tid] = 0.f;

    // base_i = b1 + h_i @ W1[0:64] -> col k=105: 16 lanes per output column
    {
      const int n = tid >> 4, part = tid & 15;
      const float* hi = &h[(b*NN + i)*HH];
      float a = 0.f;
#pragma unroll
      for (int c = 0; c < 4; ++c) a = fmaf(hi[part*4 + c], w1[(part*4 + c)*64 + n], a);
      a += __shfl_xor(a, 1); a += __shfl_xor(a, 2);
      a += __shfl_xor(a, 4); a += __shfl_xor(a, 8);
      if (part == 0) s_w1p[rowpos(n)*K1S + 105] = (__bf16)(a + b1[n]);
    }

    // per-edge geometry precompute: one thread per j (tid < 512)
    if (tid < NP) {
      const int j = tid;
      const int maski = node_mask[b*NN + i];
      const float qi0 = frames_q[(b*NN+i)*4+0], qi1 = frames_q[(b*NN+i)*4+1],
                  qi2 = frames_q[(b*NN+i)*4+2], qi3 = frames_q[(b*NN+i)*4+3];
      const float xi0 = frames_x[(b*NN+i)*3+0], xi1 = frames_x[(b*NN+i)*3+1],
                  xi2 = frames_x[(b*NN+i)*3+2];
      float qj0,qj1,qj2,qj3, xj0,xj1,xj2; int mj;
      if (j < NN) {
        const float4 q4 = *(const float4*)&frames_q[(b*NN+j)*4];
        qj0=q4.x; qj1=q4.y; qj2=q4.z; qj3=q4.w;
        xj0=frames_x[(b*NN+j)*3+0]; xj1=frames_x[(b*NN+j)*3+1]; xj2=frames_x[(b*NN+j)*3+2];
        mj = (node_mask[b*NN+j] != 0) && (j != i);
      } else {
        const int jp = j - NN;
        const float4 q4 = *(const float4*)&pocket_q[(b*PP+jp)*4];
        qj0=q4.x; qj1=q4.y; qj2=q4.z; qj3=q4.w;
        xj0=pocket_x[(b*PP+jp)*3+0]; xj1=pocket_x[(b*PP+jp)*3+1]; xj2=pocket_x[(b*PP+jp)*3+2];
        mj = (pocket_mask[b*PP+jp] != 0);
      }
      const float v0 = xi0 - xj0, v1 = xi1 - xj1, v2 = xi2 - xj2;
      const float d2 = v0*v0 + v1*v1 + v2*v2;
      const float qdot = fabsf(qi0*qj0 + qi1*qj1 + qi2*qj2 + qi3*qj3);
      const float cw = qj0, cx = -qj1, cy = -qj2, cz = -qj3;
      const float t0 = 2.f*(cy*v2 - cz*v1);
      const float t1 = 2.f*(cz*v0 - cx*v2);
      const float t2 = 2.f*(cx*v1 - cy*v0);
      const float lx0 = v0 + cw*t0 + (cy*t2 - cz*t1);
      const float lx1 = v1 + cw*t1 + (cz*t0 - cx*t2);
      const float lx2 = v2 + cw*t2 + (cx*t1 - cy*t0);
      const float lq0 = cw*qi0 - cx*qi1 - cy*qi2 - cz*qi3;
      const float lq1 = cw*qi1 + cx*qi0 + cy*qi3 - cz*qi2;
      const float lq2 = cw*qi2 - cx*qi3 + cy*qi0 + cz*qi1;
      const float lq3 = cw*qi3 + cx*qi2 - cy*qi1 + cz*qi0;
      __bf16* g = &s_geo[j*16];
      g[0]=(__bf16)lx0; g[1]=(__bf16)lx1; g[2]=(__bf16)lx2; g[3]=(__bf16)lq0;
      g[4]=(__bf16)lq1; g[5]=(__bf16)lq2; g[6]=(__bf16)lq3; g[7]=(__bf16)d2;
      g[8]=(__bf16)qdot; g[9]=(__bf16)1.f;
      g[10]=(__bf16)0.f; g[11]=(__bf16)0.f; g[12]=(__bf16)0.f;
      g[13]=(__bf16)0.f; g[14]=(__bf16)0.f; g[15]=(__bf16)0.f;
      s_maskf[j] = (maski && mj) ? 1.f : 0.f;
      const float inv = 1.f / fmaxf(sqrtf(qj0*qj0 + qj1*qj1 + qj2*qj2 + qj3*qj3), 1e-12f);
      float4* qn = (float4*)&s_qn[j*4];
      *qn = make_float4(qj0*inv, qj1*inv, qj2*inv, qj3*inv);
    }
    __syncthreads();

    float msacc[16];
#pragma unroll
    for (int v = 0; v < 16; ++v) msacc[v] = 0.f;
    float gx0 = 0.f, gx1 = 0.f, gx2 = 0.f;

    // ---- edge compute: wave wv handles one 32-edge double-strip ----
    {
      // per-node launder: keeps weight-frag/bias LDS reads inside the rep
      // loop (LICM would hoist the 24 invariant frags into registers)
      int o1 = o1base; asm volatile("" : "+v"(o1));
      int o2 = o2base; asm volatile("" : "+v"(o2));
      int ob = obbase; asm volatile("" : "+v"(ob));

      const int jbA = wv*32;
      const int jbB = jbA + 16;
      const int jA = jbA + l15, jB = jbB + l15;

      float4 hA0,hA1,hA2,hA3,eA0,eA1, hB0,hB1,hB2,hB3,eB0,eB1;
      LOADSTRIP(jbA, hA0,hA1,hA2,hA3,eA0,eA1);
      LOADSTRIP(jbB, hB0,hB1,hB2,hB3,eB0,eB1);
      const float maskA = s_maskf[jA];
      const float maskB = s_maskf[jB];

      const bf16x8 bfA0 = pack8v(hA0, hA1);
      const bf16x8 bfA1 = pack8v(hA2, hA3);
      const bf16x8 bfA2 = pack8v(eA0, eA1);
      const bf16x8 bfA3 = *(const bf16x8*)&s_geo[(lg < 2) ? (jA*16 + lg*8) : NP*16];
      const bf16x8 bfB0 = pack8v(hB0, hB1);
      const bf16x8 bfB1 = pack8v(hB2, hB3);
      const bf16x8 bfB2 = pack8v(eB0, eB1);
      const bf16x8 bfB3 = *(const bf16x8*)&s_geo[(lg < 2) ? (jB*16 + lg*8) : NP*16];

      const f32x4 zero4 = {0.f, 0.f, 0.f, 0.f};

      // ---- L1: each W1 frag read feeds both strips ----
      bf16x8 hbA0, hbA1, hbB0, hbB1;
      {
        f32x4 aA0, aA1, aB0, aB1;
        {
          const bf16x8 F0 = LDF(s_w1p, o1 + 0*16*K1S +  0);
          const bf16x8 F1 = LDF(s_w1p, o1 + 0*16*K1S + 32);
          const bf16x8 F2 = LDF(s_w1p, o1 + 0*16*K1S + 64);
          const bf16x8 F3 = LDF(s_w1p, o1 + 0*16*K1S + 96);
          aA0 = MFMA(F0,bfA0,zero4); aA0 = MFMA(F1,bfA1,aA0); aA0 = MFMA(F2,bfA2,aA0); aA0 = MFMA(F3,bfA3,aA0);
          aB0 = MFMA(F0,bfB0,zero4); aB0 = MFMA(F1,bfB1,aB0); aB0 = MFMA(F2,bfB2,aB0); aB0 = MFMA(F3,bfB3,aB0);
        }
        {
          const bf16x8 F0 = LDF(s_w1p, o1 + 1*16*K1S +  0);
          const bf16x8 F1 = LDF(s_w1p, o1 + 1*16*K1S + 32);
          const bf16x8 F2 = LDF(s_w1p, o1 + 1*16*K1S + 64);
          const bf16x8 F3 = LDF(s_w1p, o1 + 1*16*K1S + 96);
          aA1 = MFMA(F0,bfA0,zero4); aA1 = MFMA(F1,bfA1,aA1); aA1 = MFMA(F2,bfA2,aA1); aA1 = MFMA(F3,bfA3,aA1);
          aB1 = MFMA(F0,bfB0,zero4); aB1 = MFMA(F1,bfB1,aB1); aB1 = MFMA(F2,bfB2,aB1); aB1 = MFMA(F3,bfB3,aB1);
        }
#pragma unroll
        for (int r = 0; r < 4; ++r) {
          aA0[r] = fmaxf(aA0[r], 0.f); aA1[r] = fmaxf(aA1[r], 0.f);
          aB0[r] = fmaxf(aB0[r], 0.f); aB1[r] = fmaxf(aB1[r], 0.f);
        }
        hbA0 = pack8(aA0, aA1); hbB0 = pack8(aB0, aB1);
        {
          const bf16x8 F0 = LDF(s_w1p, o1 + 2*16*K1S +  0);
          const bf16x8 F1 = LDF(s_w1p, o1 + 2*16*K1S + 32);
          const bf16x8 F2 = LDF(s_w1p, o1 + 2*16*K1S + 64);
          const bf16x8 F3 = LDF(s_w1p, o1 + 2*16*K1S + 96);
          aA0 = MFMA(F0,bfA0,zero4); aA0 = MFMA(F1,bfA1,aA0); aA0 = MFMA(F2,bfA2,aA0); aA0 = MFMA(F3,bfA3,aA0);
          aB0 = MFMA(F0,bfB0,zero4); aB0 = MFMA(F1,bfB1,aB0); aB0 = MFMA(F2,bfB2,aB0); aB0 = MFMA(F3,bfB3,aB0);
        }
        {
          const bf16x8 F0 = LDF(s_w1p, o1 + 3*16*K1S +  0);
          const bf16x8 F1 = LDF(s_w1p, o1 + 3*16*K1S + 32);
          const bf16x8 F2 = LDF(s_w1p, o1 + 3*16*K1S + 64);
          const bf16x8 F3 = LDF(s_w1p, o1 + 3*16*K1S + 96);
          aA1 = MFMA(F0,bfA0,zero4); aA1 = MFMA(F1,bfA1,aA1); aA1 = MFMA(F2,bfA2,aA1); aA1 = MFMA(F3,bfA3,aA1);
          aB1 = MFMA(F0,bfB0,zero4); aB1 = MFMA(F1,bfB1,aB1); aB1 = MFMA(F2,bfB2,aB1); aB1 = MFMA(F3,bfB3,aB1);
        }
#pragma unroll
        for (int r = 0; r < 4; ++r) {
          aA0[r] = fmaxf(aA0[r], 0.f); aA1[r] = fmaxf(aA1[r], 0.f);
          aB0[r] = fmaxf(aB0[r], 0.f); aB1[r] = fmaxf(aB1[r], 0.f);
        }
        hbA1 = pack8(aA0, aA1); hbB1 = pack8(aB0, aB1);
      }

      // ---- L2: m^T tiles, shared W2 frags, laundered f32x4 bias reads ----
      bf16x8 mbA0, mbA1, mbB0, mbB1;
      {
        f32x4 cA0, cA1, cB0, cB1;
        {
          const bf16x8 F0 = LDF(s_w2p, o2 + 0*16*K2S +  0);
          const bf16x8 F1 = LDF(s_w2p, o2 + 0*16*K2S + 32);
          cA0 = MFMA(F0,hbA0,zero4); cA0 = MFMA(F1,hbA1,cA0);
          cB0 = MFMA(F0,hbB0,zero4); cB0 = MFMA(F1,hbB1,cB0);
        }
        {
          const bf16x8 F0 = LDF(s_w2p, o2 + 1*16*K2S +  0);
          const bf16x8 F1 = LDF(s_w2p, o2 + 1*16*K2S + 32);
          cA1 = MFMA(F0,hbA0,zero4); cA1 = MFMA(F1,hbA1,cA1);
          cB1 = MFMA(F0,hbB0,zero4); cB1 = MFMA(F1,hbB1,cB1);
        }
        const f32x4 bb0 = *(const f32x4*)&s_b2[ob + 0];
        const f32x4 bb1 = *(const f32x4*)&s_b2[ob + 4];
#pragma unroll
        for (int r = 0; r < 4; ++r) {
          cA0[r] = (cA0[r] + bb0[r]) * maskA;  cB0[r] = (cB0[r] + bb0[r]) * maskB;
          cA1[r] = (cA1[r] + bb1[r]) * maskA;  cB1[r] = (cB1[r] + bb1[r]) * maskB;
          msacc[0*4+r] += cA0[r] + cB0[r];
          msacc[1*4+r] += cA1[r] + cB1[r];
        }
        mbA0 = pack8(cA0, cA1); mbB0 = pack8(cB0, cB1);
        {
          const bf16x8 F0 = LDF(s_w2p, o2 + 2*16*K2S +  0);
          const bf16x8 F1 = LDF(s_w2p, o2 + 2*16*K2S + 32);
          cA0 = MFMA(F0,hbA0,zero4); cA0 = MFMA(F1,hbA1,cA0);
          cB0 = MFMA(F0,hbB0,zero4); cB0 = MFMA(F1,hbB1,cB0);
        }
        {
          const bf16x8 F0 = LDF(s_w2p, o2 + 3*16*K2S +  0);
          const bf16x8 F1 = LDF(s_w2p, o2 + 3*16*K2S + 32);
          cA1 = MFMA(F0,hbA0,zero4); cA1 = MFMA(F1,hbA1,cA1);
          cB1 = MFMA(F0,hbB0,zero4); cB1 = MFMA(F1,hbB1,cB1);
        }
        const f32x4 bb2 = *(const f32x4*)&s_b2[ob + 32];
        const f32x4 bb3 = *(const f32x4*)&s_b2[ob + 36];
#pragma unroll
        for (int r = 0; r < 4; ++r) {
          cA0[r] = (cA0[r] + bb2[r]) * maskA;  cB0[r] = (cB0[r] + bb2[r]) * maskB;
          cA1[r] = (cA1[r] + bb3[r]) * maskA;  cB1[r] = (cB1[r] + bb3[r]) * maskB;
          msacc[2*4+r] += cA0[r] + cB0[r];
          msacc[3*4+r] += cA1[r] + cB1[r];
        }
        mbA1 = pack8(cA0, cA1); mbB1 = pack8(cB0, cB1);
      }

      // ---- tr1: th^T tiles, shared tw1 frags ----
      bf16x8 thbA0, thbA1, thbB0, thbB1;
      {
        f32x4 dA0, dA1, dB0, dB1;
        {
          const bf16x8 F0 = LDF(s_tw1p, o2 + 0*16*K2S +  0);
          const bf16x8 F1 = LDF(s_tw1p, o2 + 0*16*K2S + 32);
          dA0 = MFMA(F0,mbA0,zero4); dA0 = MFMA(F1,mbA1,dA0);
          dB0 = MFMA(F0,mbB0,zero4); dB0 = MFMA(F1,mbB1,dB0);
        }
        {
          const bf16x8 F0 = LDF(s_tw1p, o2 + 1*16*K2S +  0);
          const bf16x8 F1 = LDF(s_tw1p, o2 + 1*16*K2S + 32);
          dA1 = MFMA(F0,mbA0,zero4); dA1 = MFMA(F1,mbA1,dA1);
          dB1 = MFMA(F0,mbB0,zero4); dB1 = MFMA(F1,mbB1,dB1);
        }
        {
          const f32x4 tb0 = *(const f32x4*)&s_tb1[ob + 0];
          const f32x4 tb1v = *(const f32x4*)&s_tb1[ob + 4];
#pragma unroll
          for (int r = 0; r < 4; ++r) {
            dA0[r] = fmaxf(dA0[r] + tb0[r], 0.f);  dB0[r] = fmaxf(dB0[r] + tb0[r], 0.f);
            dA1[r] = fmaxf(dA1[r] + tb1v[r], 0.f); dB1[r] = fmaxf(dB1[r] + tb1v[r], 0.f);
          }
        }
        thbA0 = pack8(dA0, dA1); thbB0 = pack8(dB0, dB1);
        {
          const bf16x8 F0 = LDF(s_tw1p, o2 + 2*16*K2S +  0);
          const bf16x8 F1 = LDF(s_tw1p, o2 + 2*16*K2S + 32);
          dA0 = MFMA(F0,mbA0,zero4); dA0 = MFMA(F1,mbA1,dA0);
          dB0 = MFMA(F0,mbB0,zero4); dB0 = MFMA(F1,mbB1,dB0);
        }
        {
          const bf16x8 F0 = LDF(s_tw1p, o2 + 3*16*K2S +  0);
          const bf16x8 F1 = LDF(s_tw1p, o2 + 3*16*K2S + 32);
          dA1 = MFMA(F0,mbA0,zero4); dA1 = MFMA(F1,mbA1,dA1);
          dB1 = MFMA(F0,mbB0,zero4); dB1 = MFMA(F1,mbB1,dB1);
        }
        {
          const f32x4 tb2v = *(const f32x4*)&s_tb1[ob + 32];
          const f32x4 tb3v = *(const f32x4*)&s_tb1[ob + 36];
#pragma unroll
          for (int r = 0; r < 4; ++r) {
            dA0[r] = fmaxf(dA0[r] + tb2v[r], 0.f);  dB0[r] = fmaxf(dB0[r] + tb2v[r], 0.f);
            dA1[r] = fmaxf(dA1[r] + tb3v[r], 0.f);  dB1[r] = fmaxf(dB1[r] + tb3v[r], 0.f);
          }
        }
        thbA1 = pack8(dA0, dA1); thbB1 = pack8(dB0, dB1);
      }

      // ---- dx: 2 MFMAs per strip with tw2^T (rows 0..2 = dims) ----
      f32x4 daccA = MFMA(tw2f[0], thbA0, zero4);
      daccA = MFMA(tw2f[1], thbA1, daccA);
      f32x4 daccB = MFMA(tw2f[0], thbB0, zero4);
      daccB = MFMA(tw2f[1], thbB1, daccB);

      if (lg == 0) {
        {
          const float dx0 = (daccA[0] + tb2r0) * maskA;
          const float dx1 = (daccA[1] + tb2r1) * maskA;
          const float dx2 = (daccA[2] + tb2r2) * maskA;
          const float4 qn = *(const float4*)&s_qn[jA*4];
          const float w = qn.x, ux = qn.y, uy = qn.z, uz = qn.w;
          const float r0 = 2.f*(uy*dx2 - uz*dx1);
          const float r1 = 2.f*(uz*dx0 - ux*dx2);
          const float r2 = 2.f*(ux*dx1 - uy*dx0);
          gx0 += dx0 + w*r0 + (uy*r2 - uz*r1);
          gx1 += dx1 + w*r1 + (uz*r0 - ux*r2);
          gx2 += dx2 + w*r2 + (ux*r1 - uy*r0);
        }
        {
          const float dx0 = (daccB[0] + tb2r0) * maskB;
          const float dx1 = (daccB[1] + tb2r1) * maskB;
          const float dx2 = (daccB[2] + tb2r2) * maskB;
          const float4 qn = *(const float4*)&s_qn[jB*4];
          const float w = qn.x, ux = qn.y, uy = qn.z, uz = qn.w;
          const float r0 = 2.f*(uy*dx2 - uz*dx1);
          const float r1 = 2.f*(uz*dx0 - ux*dx2);
          const float r2 = 2.f*(ux*dx1 - uy*dx0);
          gx0 += dx0 + w*r0 + (uy*r2 - uz*r1);
          gx1 += dx1 + w*r1 + (uz*r0 - ux*r2);
          gx2 += dx2 + w*r2 + (ux*r1 - uy*r0);
        }
      }
    }

    // ---- epilogue: msum (reduce over the 16 l15 lanes), gdx ----
#pragma unroll
    for (int v = 0; v < 16; ++v) {
      float x = msacc[v];
      x += __shfl_xor(x, 1); x += __shfl_xor(x, 2);
      x += __shfl_xor(x, 4); x += __shfl_xor(x, 8);
      if (l15 == 0) {
        const int n2 = (v>>3)*32 + lg*8 + ((v>>2)&1)*4 + (v&3);
        atomicAdd(&s_msum[n2], x);
      }
    }
    {
      float v0 = (lg == 0) ? gx0 : 0.f;
      float v1 = (lg == 0) ? gx1 : 0.f;
      float v2 = (lg == 0) ? gx2 : 0.f;
#pragma unroll
      for (int sft = 1; sft < 64; sft <<= 1) {
        v0 += __shfl_xor(v0, sft); v1 += __shfl_xor(v1, sft); v2 += __shfl_xor(v2, sft);
      }
      if (lane == 0) { atomicAdd(&s_gdx[0], v0); atomicAdd(&s_gdx[1], v1); atomicAdd(&s_gdx[2], v2); }
    }
    __syncthreads();
    if (tid < 64) msum_ws[ni*64 + tid] = s_msum[tid];
    if (tid >= 64 && tid < 67) gdx_ws[ni*3 + (tid - 64)] = s_gdx[tid - 64];
  }
#undef LOADSTRIP
}

// One block (1 wave) per (b, i): o, dq->upd_q, upd_x, torsions.
__global__ __launch_bounds__(64) void egnn_node_kernel(
    const float* __restrict__ frames_q, const float* __restrict__ frames_x,
    const float* __restrict__ h,
    const int* __restrict__ node_mask, const int* __restrict__ pocket_mask,
    const float* __restrict__ fw1, const float* __restrict__ fb1,
    const float* __restrict__ fw2, const float* __restrict__ fb2,
    const float* __restrict__ qw1, const float* __restrict__ qb1,
    const float* __restrict__ qw2, const float* __restrict__ qb2,
    const float* __restrict__ tow1, const float* __restrict__ tob1,
    const float* __restrict__ tow2, const float* __restrict__ tob2,
    const float* __restrict__ msum_ws, const float* __restrict__ gdx_ws,
    float* __restrict__ out)
{
  const int t  = threadIdx.x;
  const int bi = blockIdx.x;
  const int b = bi / NN, i = bi % NN;
  __shared__ float s_h[64], s_ms[64], s_hid[64], s_tmp[16];

  s_h[t]  = h[(b*NN+i)*HH + t];
  s_ms[t] = msum_ws[(b*NN+i)*64 + t];

  int cnt = 0;
  for (int k = t; k < NN; k += 64) cnt += (node_mask[b*NN+k] != 0);
  for (int k = t; k < PP; k += 64) cnt += (pocket_mask[b*PP+k] != 0);
  cnt += __shfl_xor(cnt,1); cnt += __shfl_xor(cnt,2); cnt += __shfl_xor(cnt,4);
  cnt += __shfl_xor(cnt,8); cnt += __shfl_xor(cnt,16); cnt += __shfl_xor(cnt,32);
  const float n_nb = (float)(cnt - 1);

  __syncthreads();
  float a = fb1[t];
  for (int k = 0; k < 64; ++k) a = fmaf(s_h[k],  fw1[k*64 + t], a);
  for (int k = 0; k < 64; ++k) a = fmaf(s_ms[k], fw1[(64+k)*64 + t], a);
  s_hid[t] = fmaxf(a, 0.f);
  __syncthreads();
  float ov = fb2[t];
  for (int k = 0; k < 64; ++k) ov = fmaf(s_hid[k], fw2[k*64 + t], ov);
  out[O_OFF + (b*NN+i)*64 + t] = ov;

  __syncthreads();
  float aq = qb1[t];
  for (int k = 0; k < 64; ++k) aq = fmaf(s_ms[k], qw1[k*64 + t], aq);
  s_hid[t] = fmaxf(aq, 0.f);
  __syncthreads();
  if (t < 4) {
    float d = qb2[t];
    for (int k = 0; k < 64; ++k) d = fmaf(s_hid[k], qw2[k*4 + t], d);
    s_tmp[t] = d;
  }
  __syncthreads();
  if (t == 0) {
    const int mi = node_mask[b*NN+i];
    float d0,d1,d2,d3;
    if (mi) { d0=s_tmp[0]; d1=s_tmp[1]; d2=s_tmp[2]; d3=s_tmp[3]; }
    else    { d0=1.f; d1=0.f; d2=0.f; d3=0.f; }
    float nrm = fmaxf(sqrtf(d0*d0+d1*d1+d2*d2+d3*d3), 1e-12f);
    d0/=nrm; d1/=nrm; d2/=nrm; d3/=nrm;
    const float q0=frames_q[(b*NN+i)*4+0], q1=frames_q[(b*NN+i)*4+1],
                q2=frames_q[(b*NN+i)*4+2], q3=frames_q[(b*NN+i)*4+3];
    float u0 = q0*d0 - q1*d1 - q2*d2 - q3*d3;
    float u1 = q0*d1 + q1*d0 + q2*d3 - q3*d2;
    float u2 = q0*d2 - q1*d3 + q2*d0 + q3*d1;
    float u3 = q0*d3 + q1*d2 - q2*d1 + q3*d0;
    if (!mi) { u0=1.f; u1=0.f; u2=0.f; u3=0.f; }
    float nrm2 = fmaxf(sqrtf(u0*u0+u1*u1+u2*u2+u3*u3), 1e-12f);
    out[(b*NN+i)*4+0]=u0/nrm2; out[(b*NN+i)*4+1]=u1/nrm2;
    out[(b*NN+i)*4+2]=u2/nrm2; out[(b*NN+i)*4+3]=u3/nrm2;
  }
  if (t < 3) {
    out[X_OFF + (b*NN+i)*3 + t] = frames_x[(b*NN+i)*3+t] + gdx_ws[(b*NN+i)*3+t] / n_nb;
  }

  __syncthreads();
  float at = tob1[t];
  for (int k = 0; k < 64; ++k) at = fmaf(s_ms[k], tow1[k*64 + t], at);
  s_hid[t] = fmaxf(at, 0.f);
  __syncthreads();
  if (t < 14) {
    float v = tob2[t];
    for (int k = 0; k < 64; ++k) v = fmaf(s_hid[k], tow2[k*14 + t], v);
    s_tmp[t] = v;
  }
  __syncthreads();
  if (t < 14) {
    const int p = t & ~1;
    const float a0 = s_tmp[p], a1 = s_tmp[p+1];
    const float nrm = fmaxf(sqrtf(a0*a0 + a1*a1), 1e-12f);
    out[T_OFF + (b*NN+i)*14 + t] = s_tmp[t] / nrm;
  }
}

extern "C" void kernel_launch(void* const* d_in, const int* in_sizes, int n_in,
                              void* d_out, int out_size, void* d_ws, size_t ws_size,
                              hipStream_t stream) {
  const float* frames_q    = (const float*)d_in[0];
  const float* frames_x    = (const float*)d_in[1];
  const float* h           = (const float*)d_in[3];
  const float* e           = (const float*)d_in[4];
  const int*   node_mask   = (const int*)d_in[5];
  const float* pocket_h    = (const float*)d_in[6];
  const float* pocket_e    = (const float*)d_in[7];
  const float* pocket_q    = (const float*)d_in[8];
  const float* pocket_x    = (const float*)d_in[9];
  const int*   pocket_mask = (const int*)d_in[10];
  const float* msg_w1 = (const float*)d_in[11];
  const float* msg_b1 = (const float*)d_in[12];
  const float* msg_w2 = (const float*)d_in[13];
  const float* msg_b2 = (const float*)d_in[14];
  const float* feat_w1 = (const float*)d_in[15];
  const float* feat_b1 = (const float*)d_in[16];
  const float* feat_w2 = (const float*)d_in[17];
  const float* feat_b2 = (const float*)d_in[18];
  const float* tr_w1 = (const float*)d_in[19];
  const float* tr_b1 = (const float*)d_in[20];
  const float* tr_w2 = (const float*)d_in[21];
  const float* tr_b2 = (const float*)d_in[22];
  const float* qu_w1 = (const float*)d_in[23];
  const float* qu_b1 = (const float*)d_in[24];
  const float* qu_w2 = (const float*)d_in[25];
  const float* qu_b2 = (const float*)d_in[26];
  const float* to_w1 = (const float*)d_in[27];
  const float* to_b1 = (const float*)d_in[28];
  const float* to_w2 = (const float*)d_in[29];
  const float* to_b2 = (const float*)d_in[30];

  float* out = (float*)d_out;
  float* msum_ws = (float*)d_ws;                 // B*N*64 floats
  float* gdx_ws  = msum_ws + BB*NN*64;           // B*N*3 floats

  egnn_edge_persist<<<dim3(256), dim3(1024), 0, stream>>>(
      frames_q, frames_x, h, e, node_mask,
      pocket_h, pocket_e, pocket_q, pocket_x, pocket_mask,
      msg_w1, msg_b1, msg_w2, msg_b2,
      tr_w1, tr_b1, tr_w2, tr_b2,
      msum_ws, gdx_ws);

  egnn_node_kernel<<<dim3(BB*NN), dim3(64), 0, stream>>>(
      frames_q, frames_x, h, node_mask, pocket_mask,
      feat_w1, feat_b1, feat_w2, feat_b2,
      qu_w1, qu_b1, qu_w2, qu_b2,
      to_w1, to_b1, to_w2, to_b2,
      msum_ws, gdx_ws, out);
}